// Round 14
// baseline (449.573 us; speedup 1.0000x reference)
//
#include <hip/hip_runtime.h>
#include <hip/hip_fp16.h>
#include <cstdint>
#include <cstring>

typedef unsigned int uint;

#define BSHIFT 8          // 256 nodes per bucket
#define NBUCK 512         // max buckets (N up to 131072)
#define TILE 4096         // scatter tile
#define FUSE_T 1024       // fused sort+gat block size
#define LS_T 512          // fused linear+scatter block size
#define SORT_CAP 5120     // per-bucket capacity (mean ~4092, +16 sigma)

__device__ __forceinline__ float leaky02(float x) { return x > 0.f ? x : 0.2f * x; }
__device__ __forceinline__ float bflo(uint u) { return __uint_as_float(u << 16); }
__device__ __forceinline__ float bfhi(uint u) { return __uint_as_float(u & 0xffff0000u); }

__device__ __forceinline__ uint pack_bf16x2(float a, float b) {
    uint ua = __float_as_uint(a), ub = __float_as_uint(b);
    ua += 0x7fffu + ((ua >> 16) & 1u);
    ub += 0x7fffu + ((ub >> 16) & 1u);
    return (ua >> 16) | (ub & 0xffff0000u);
}

__device__ __forceinline__ uint packh2(float a, float b) {
    __half ha = __float2half_rn(a), hb = __float2half_rn(b);
    unsigned short ua, ub;
    memcpy(&ua, &ha, 2);
    memcpy(&ub, &hb, 2);
    return (uint)ua | ((uint)ub << 16);
}

// select half #head (0..3) from a uint2 of 4 packed halves via bit ops
__device__ __forceinline__ float h2f_sel(uint2 xw, int head) {
    uint wrd = (head & 2) ? xw.y : xw.x;
    unsigned short us = (unsigned short)((head & 1) ? (wrd >> 16) : (wrd & 0xffffu));
    __half hh; memcpy(&hh, &us, 2);
    return __half2float(hh);
}

// ---------------------------------------------------------------------------
// FUSED k_linear + kb_scatter (independent work, block-range split).
// Blocks [0, Lb): linear — 64 nodes/block. Blocks [Lb, Lb+Sb): scatter —
// one 4096-edge tile/block, direct-write placement (R13-measured neutral,
// simpler). cursor/sums/sumsq/done zeroed by hipMemsetAsync before launch.
// ---------------------------------------------------------------------------
__global__ void k_linscat(const float* __restrict__ x, const float* __restrict__ W,
                          const float* __restrict__ att_s, const float* __restrict__ att_d,
                          uint* __restrict__ h, float* __restrict__ a_src,
                          float* __restrict__ a_dst,
                          const int* __restrict__ src, const int* __restrict__ dst, int E,
                          int* __restrict__ cursor, uint* __restrict__ pairs,
                          int N, int Lb) {
    int tid = threadIdx.x;  // 512
    if (blockIdx.x < Lb) {
        // ---------------- linear part: 64 nodes ----------------
        __shared__ float sx[64][16];
        __shared__ float sWs[64], sWd[64];
        int j = tid & 63;       // channel pair
        int sub = tid >> 6;     // wave id 0..7 -> node subgroup
        int n0 = blockIdx.x * 64;

        float2 wreg[16];
#pragma unroll
        for (int k = 0; k < 16; k++) wreg[k] = ((const float2*)(W + k * 128))[j];

        if (tid < 256) {
            int row = tid >> 2;
            if (n0 + row < N)
                ((float4*)sx)[tid] = ((const float4*)(x + (size_t)n0 * 16))[tid];
        } else if (tid < 320) {
            int t = tid - 256;              // t = k*4 + hh
            int k = t >> 2, hh = t & 3;
            float s1 = 0.f, s2 = 0.f;
            for (int c = 0; c < 32; c++) {
                float wv = W[k * 128 + hh * 32 + c];
                s1 += wv * att_s[hh * 32 + c];
                s2 += wv * att_d[hh * 32 + c];
            }
            sWs[t] = s1;
            sWd[t] = s2;
        }
        __syncthreads();

#pragma unroll
        for (int i = 0; i < 8; i++) {
            int loc = sub + i * 8;
            int n = n0 + loc;
            if (n >= N) break;
            float acc0 = 0.f, acc1 = 0.f;
#pragma unroll
            for (int k = 0; k < 16; k++) {
                float xk = sx[loc][k];
                acc0 += xk * wreg[k].x;
                acc1 += xk * wreg[k].y;
            }
            h[(size_t)n * 64 + j] = pack_bf16x2(acc0, acc1);
        }

        // a_src / a_dst: thread t -> (node tid>>3, head (tid>>1)&3, sd tid&1)
        int loc2 = tid >> 3, hh = (tid >> 1) & 3, sd = tid & 1;
        int n2 = n0 + loc2;
        if (n2 < N) {
            const float* Wm = sd ? sWd : sWs;
            float acc = 0.f;
#pragma unroll
            for (int k = 0; k < 16; k++) acc += sx[loc2][k] * Wm[k * 4 + hh];
            if (sd) a_dst[n2 * 4 + hh] = acc;
            else    a_src[n2 * 4 + hh] = acc;
        }
    } else {
        // ---------------- scatter part: one 4096-edge tile, direct write ---
        __shared__ int tileCnt[NBUCK], tileCnt2[NBUCK], gbase[NBUCK];
        int bid = blockIdx.x - Lb;
        int t0 = bid * TILE;
        tileCnt[tid] = 0;
        tileCnt2[tid] = 0;
        __syncthreads();
        int dreg[8], sreg[8];
#pragma unroll
        for (int jj = 0; jj < 8; jj++) {
            int idx = t0 + jj * LS_T + tid;
            if (idx < E) {
                dreg[jj] = dst[idx];
                sreg[jj] = src[idx];
                atomicAdd(&tileCnt[dreg[jj] >> BSHIFT], 1);
            } else dreg[jj] = -1;
        }
        __syncthreads();
        int v = tileCnt[tid];
        if (v > 0) gbase[tid] = atomicAdd(&cursor[tid], v);
        __syncthreads();
#pragma unroll
        for (int jj = 0; jj < 8; jj++) {
            if (dreg[jj] >= 0) {
                int bk = dreg[jj] >> BSHIFT;
                int r = atomicAdd(&tileCnt2[bk], 1);
                int pos = gbase[bk] + r;
                if (pos < SORT_CAP)
                    pairs[(size_t)bk * SORT_CAP + pos] =
                        ((uint)sreg[jj] << BSHIFT) | (uint)(dreg[jj] & 255);
            }
        }
    }
}

// ---------------------------------------------------------------------------
// FUSED per-bucket sort + GAT aggregation + BN stats + (last block) MLP.
// Core = R11-measured config (73.4 us): register sv/sq BN + one post-loop
// reduction; mild spill is overlappable and measured-free (do NOT move BN
// into the pass loop — R12 cost +22 us). hagg written unconditionally
// (flags-gating measured as zero benefit in R8).
// Last-block-done pattern absorbs k_mlp: saves one kernel launch; the MLP
// runs 2-nodes-per-wave (all 64 lanes used in the 128x32 dot).
// ---------------------------------------------------------------------------
__global__ void __launch_bounds__(1024, 8) kb_sortgat(
                           const uint* __restrict__ pairs, const int* __restrict__ cursor,
                           const float* __restrict__ a_src, const float* __restrict__ a_dst,
                           const uint* __restrict__ h, const float* __restrict__ bias,
                           uint* __restrict__ hagg,
                           float* __restrict__ sums, float* __restrict__ sumsq,
                           int* __restrict__ done,
                           const int* __restrict__ lut, int nlut,
                           const float* __restrict__ gamma, const float* __restrict__ beta,
                           const float* __restrict__ W1, const float* __restrict__ b1,
                           const float* __restrict__ W2, const float* __restrict__ b2,
                           float* __restrict__ out, int N) {
    __shared__ int cnt[256], off0[256], degl[256];
    __shared__ int wsum[4], wbase[4];
    __shared__ uint lcode[SORT_CAP];      // src per edge; reused: BN-reduce, MLP v
    __shared__ uint2 wlds[SORT_CAP];      // fp16x4 weights; reused: MLP W1/stats
    __shared__ float4 sad[256];
    __shared__ float4 sbias[32];
    __shared__ int lastFlag;
    int tid = threadIdx.x;  // 1024
    int l = tid & 63, w = tid >> 6;
    int b = blockIdx.x;
    int n0 = b << BSHIFT;
    int nn = min(256, N - n0);
    int ebase = b * SORT_CAP;
    int ecnt = cursor[b];
    if (ecnt > SORT_CAP) ecnt = SORT_CAP;
    if (tid < 256) cnt[tid] = 0;
    if (tid < nn) sad[tid] = ((const float4*)a_dst)[n0 + tid];
    if (tid >= 992) sbias[tid - 992] = ((const float4*)bias)[tid - 992];
    __syncthreads();
    for (int k = tid; k < ecnt; k += FUSE_T)
        atomicAdd(&cnt[pairs[ebase + k] & 255], 1);
    __syncthreads();
    // wave-shfl exclusive scan over 256 entries (waves 0..3)
    int v = (tid < 256) ? cnt[tid] : 0;
    int s = v;
#pragma unroll
    for (int off = 1; off < 64; off <<= 1) {
        int t = __shfl_up(s, off);
        if (l >= off) s += t;
    }
    if (tid < 256 && l == 63) wsum[w] = s;
    __syncthreads();
    if (tid < 4) {
        int base = 0;
        for (int i = 0; i < tid; i++) base += wsum[i];
        wbase[tid] = base;
    }
    __syncthreads();
    if (tid < 256) {
        off0[tid] = s - v + wbase[w];
        degl[tid] = v;
    }
    __syncthreads();
    if (tid < 256) cnt[tid] = 0;
    __syncthreads();
    // single pass: scatter src + compute weights (a_src is L2-resident)
    for (int k = tid; k < ecnt; k += FUSE_T) {
        uint p = pairs[ebase + k];
        int ln = p & 255;
        int src = (int)(p >> BSHIFT);
        int r = atomicAdd(&cnt[ln], 1);
        int pos = off0[ln] + r;
        lcode[pos] = (uint)src;
        float4 as = ((const float4*)a_src)[src];
        float4 ad = sad[ln];
        wlds[pos] = make_uint2(
            packh2(__expf(leaky02(as.x + ad.x)), __expf(leaky02(as.y + ad.y))),
            packh2(__expf(leaky02(as.z + ad.z)), __expf(leaky02(as.w + ad.w))));
    }
    __syncthreads();
    // aggregation: 16 waves x 4 nodes/wave = 64 nodes per pass, 4 passes
    int q = l >> 4;
    int l16 = l & 15;
    int head = l16 >> 2;
    float sv[8], sq[8];
#pragma unroll
    for (int j = 0; j < 8; j++) { sv[j] = 0.f; sq[j] = 0.f; }
    for (int pass = 0; pass < 4; pass++) {
        int ln = pass * 64 + w * 4 + q;
        if (ln >= nn) continue;   // no barriers below in this loop: safe
        int d = n0 + ln;
        int ebs = off0[ln];
        int deg = degl[ln];
        float asv = a_src[d * 4 + head];
        float adv = ((const float*)sad)[ln * 4 + head];
        float wslf = __expf(leaky02(asv + adv));
        uint4 u = ((const uint4*)(h + (size_t)d * 64))[l16];
        float sum = wslf;
        float2 a01 = make_float2(wslf * bflo(u.x), wslf * bfhi(u.x));
        float2 a23 = make_float2(wslf * bflo(u.y), wslf * bfhi(u.y));
        float2 a45 = make_float2(wslf * bflo(u.z), wslf * bfhi(u.z));
        float2 a67 = make_float2(wslf * bflo(u.w), wslf * bfhi(u.w));

        int i = 0;
        for (; i + 1 < deg; i += 2) {
            uint p0 = lcode[ebs + i];
            uint p1 = lcode[ebs + i + 1];
            float w0 = h2f_sel(wlds[ebs + i], head);
            float w1 = h2f_sel(wlds[ebs + i + 1], head);
            uint4 u0 = ((const uint4*)(h + (size_t)p0 * 64))[l16];
            uint4 u1 = ((const uint4*)(h + (size_t)p1 * 64))[l16];
            sum += w0 + w1;
            float2 w02 = {w0, w0}, w12 = {w1, w1};
            a01 += make_float2(bflo(u0.x), bfhi(u0.x)) * w02
                 + make_float2(bflo(u1.x), bfhi(u1.x)) * w12;
            a23 += make_float2(bflo(u0.y), bfhi(u0.y)) * w02
                 + make_float2(bflo(u1.y), bfhi(u1.y)) * w12;
            a45 += make_float2(bflo(u0.z), bfhi(u0.z)) * w02
                 + make_float2(bflo(u1.z), bfhi(u1.z)) * w12;
            a67 += make_float2(bflo(u0.w), bfhi(u0.w)) * w02
                 + make_float2(bflo(u1.w), bfhi(u1.w)) * w12;
        }
        if (i < deg) {
            uint p0 = lcode[ebs + i];
            float w0 = h2f_sel(wlds[ebs + i], head);
            uint4 u0 = ((const uint4*)(h + (size_t)p0 * 64))[l16];
            sum += w0;
            float2 w02 = {w0, w0};
            a01 += make_float2(bflo(u0.x), bfhi(u0.x)) * w02;
            a23 += make_float2(bflo(u0.y), bfhi(u0.y)) * w02;
            a45 += make_float2(bflo(u0.z), bfhi(u0.z)) * w02;
            a67 += make_float2(bflo(u0.w), bfhi(u0.w)) * w02;
        }
        float inv = 1.f / sum;
        float4 b0 = sbias[2 * l16];
        float4 b1v = sbias[2 * l16 + 1];
        float v0 = a01.x * inv + b0.x;
        float v1 = a01.y * inv + b0.y;
        float v2 = a23.x * inv + b0.z;
        float v3 = a23.y * inv + b0.w;
        float v4 = a45.x * inv + b1v.x;
        float v5 = a45.y * inv + b1v.y;
        float v6 = a67.x * inv + b1v.z;
        float v7 = a67.y * inv + b1v.w;
        sv[0] += v0; sq[0] += v0 * v0;
        sv[1] += v1; sq[1] += v1 * v1;
        sv[2] += v2; sq[2] += v2 * v2;
        sv[3] += v3; sq[3] += v3 * v3;
        sv[4] += v4; sq[4] += v4 * v4;
        sv[5] += v5; sq[5] += v5 * v5;
        sv[6] += v6; sq[6] += v6 * v6;
        sv[7] += v7; sq[7] += v7 * v7;
        {
            uint4 o;
            o.x = pack_bf16x2(v0, v1);
            o.y = pack_bf16x2(v2, v3);
            o.z = pack_bf16x2(v4, v5);
            o.w = pack_bf16x2(v6, v7);
            ((uint4*)(hagg + (size_t)d * 64))[l16] = o;
        }
    }
    // BN stats reduction: shfl over node-groups (lane bits 4,5), then LDS
    __syncthreads();               // all lcode/wlds reads done -> reuse lcode
#pragma unroll
    for (int j = 0; j < 8; j++) {
        sv[j] += __shfl_xor(sv[j], 16);
        sv[j] += __shfl_xor(sv[j], 32);
        sq[j] += __shfl_xor(sq[j], 16);
        sq[j] += __shfl_xor(sq[j], 32);
    }
    float* red = (float*)lcode;    // 256 rows x 16 floats = 16 KB <= 20 KB
    if (l < 16) {
#pragma unroll
        for (int j = 0; j < 8; j++) {
            red[(w * 16 + l) * 16 + j] = sv[j];
            red[(w * 16 + l) * 16 + 8 + j] = sq[j];
        }
    }
    __syncthreads();
    if (tid < 256) {
        int lg = tid >> 4, j = tid & 15;
        float tot = 0.f;
#pragma unroll
        for (int ww = 0; ww < 16; ww++) tot += red[(ww * 16 + lg) * 16 + j];
        if (j < 8) atomicAdd(&sums[lg * 8 + j], tot);
        else       atomicAdd(&sumsq[lg * 8 + j - 8], tot);
    }
    // ---- last-block-done MLP (absorbs the k_mlp launch) ----
    __syncthreads();
    __threadfence();               // release: hagg + BN atomics visible
    if (tid == 0) {
        int old = atomicAdd(done, 1);
        lastFlag = (old == (int)gridDim.x - 1);
    }
    __syncthreads();
    if (!lastFlag) return;
    __threadfence();               // acquire: see other blocks' writes
    float* w1s  = (float*)wlds;    // 4096 floats (16 KB) in wlds (40 KB)
    float* sgam = w1s + 4096;      // 128
    float* sbet = sgam + 128;      // 128
    float* sb1  = sbet + 128;      // 32
    float* sw2  = sb1 + 32;        // 32
    float* smean= sw2 + 32;        // 128
    float* svar = smean + 128;     // 128
    float* vbuf = (float*)lcode;   // 16 waves x 256 floats (16 KB) in lcode
    for (int k = tid; k < 4096; k += FUSE_T) w1s[k] = W1[k];
    float invN = 1.f / (float)N;
    if (tid < 128) {
        sgam[tid] = gamma[tid];
        sbet[tid] = beta[tid];
        float sm = atomicAdd(&sums[tid], 0.f);    // device-scope atomic load
        float s2 = atomicAdd(&sumsq[tid], 0.f);
        float mean = sm * invN;
        smean[tid] = mean;
        svar[tid] = s2 * invN - mean * mean;
    } else if (tid < 160) {
        sb1[tid - 128] = b1[tid - 128];
        sw2[tid - 128] = W2[tid - 128];
    }
    __syncthreads();
    float b2v = b2[0];
    int lane2 = l & 31, half = l >> 5;
    float* v0p = vbuf + w * 256;
    float* v1p = v0p + 128;
    for (int base = 0; base < nlut; base += 32) {
        int i0 = base + 2 * w;     // wave w handles nodes i0, i0+1
        if (i0 < nlut) {
            int nd = lut[i0];
            uint uu = hagg[(size_t)nd * 64 + l];
            int c0 = 2 * l, c1 = c0 + 1;
            v0p[c0] = fmaxf((bflo(uu) - smean[c0]) / sqrtf(svar[c0] + 1e-5f) * sgam[c0] + sbet[c0], 0.f);
            v0p[c1] = fmaxf((bfhi(uu) - smean[c1]) / sqrtf(svar[c1] + 1e-5f) * sgam[c1] + sbet[c1], 0.f);
        }
        if (i0 + 1 < nlut) {
            int nd = lut[i0 + 1];
            uint uu = hagg[(size_t)nd * 64 + l];
            int c0 = 2 * l, c1 = c0 + 1;
            v1p[c0] = fmaxf((bflo(uu) - smean[c0]) / sqrtf(svar[c0] + 1e-5f) * sgam[c0] + sbet[c0], 0.f);
            v1p[c1] = fmaxf((bfhi(uu) - smean[c1]) / sqrtf(svar[c1] + 1e-5f) * sgam[c1] + sbet[c1], 0.f);
        }
        int idx = i0 + half;
        if (idx < nlut) {
            const float* vv = half ? v1p : v0p;
            float z = sb1[lane2];
            for (int c = 0; c < 128; c++) z += vv[c] * w1s[c * 32 + lane2];
            z = z > 0.f ? z : 0.01f * z;
            float r = z * sw2[lane2];
#pragma unroll
            for (int off2 = 16; off2 >= 1; off2 >>= 1) r += __shfl_xor(r, off2, 32);
            if (lane2 == 0) out[idx] = r + b2v;
        }
    }
}

// ---------------------------------------------------------------------------
extern "C" void kernel_launch(void* const* d_in, const int* in_sizes, int n_in,
                              void* d_out, int out_size, void* d_ws, size_t ws_size,
                              hipStream_t stream) {
    const float* x     = (const float*)d_in[0];
    const int*   edges = (const int*)d_in[1];
    const int*   lut   = (const int*)d_in[2];
    const float* W_lin = (const float*)d_in[3];
    const float* att_s = (const float*)d_in[4];
    const float* att_d = (const float*)d_in[5];
    const float* bias  = (const float*)d_in[6];
    const float* gamma = (const float*)d_in[7];
    const float* beta  = (const float*)d_in[8];
    const float* W1    = (const float*)d_in[9];
    const float* b1    = (const float*)d_in[10];
    const float* W2    = (const float*)d_in[11];
    const float* b2    = (const float*)d_in[12];

    int N = in_sizes[0] / 16;
    int E = in_sizes[1] / 2;
    int nlut = in_sizes[2];
    int B = (N + 255) >> BSHIFT;   // 391 for N=100000
    int Lb = (N + 63) / 64;        // linear blocks (64 nodes each)
    int Sb = (E + TILE - 1) / TILE;

    const int* esrc = edges;
    const int* edst = edges + E;

    char* ws = (char*)d_ws;
    size_t off = 0;
    auto alloc = [&](size_t bytes) -> void* {
        void* p = ws + off;
        off += (bytes + 255) & ~(size_t)255;
        return p;
    };
    uint*  h       = (uint*)alloc((size_t)N * 64 * 4);          // bf16x2 [N,128]
    uint*  hagg    = (uint*)alloc((size_t)N * 64 * 4);          // bf16x2 [N,128]
    float* a_src   = (float*)alloc((size_t)N * 4 * 4);
    float* a_dst   = (float*)alloc((size_t)N * 4 * 4);
    uint*  pairs   = (uint*)alloc((size_t)B * SORT_CAP * 4);
    // contiguous zero-region: cursor | sums | sumsq | done
    char*  zbase   = ws + off;
    int*   cursor  = (int*)alloc((size_t)NBUCK * 4);
    float* sums    = (float*)alloc(128 * 4);
    float* sumsq   = (float*)alloc(128 * 4);
    int*   done    = (int*)alloc(256);
    size_t zspan = (size_t)((ws + off) - zbase);

    hipMemsetAsync(zbase, 0, zspan, stream);
    k_linscat<<<Lb + Sb, LS_T, 0, stream>>>(x, W_lin, att_s, att_d, h, a_src, a_dst,
                                            esrc, edst, E, cursor, pairs, N, Lb);
    kb_sortgat<<<B, FUSE_T, 0, stream>>>(pairs, cursor, a_src, a_dst, h, bias,
                                         hagg, sums, sumsq, done, lut, nlut,
                                         gamma, beta, W1, b1, W2, b2,
                                         (float*)d_out, N);
}

// Round 15
// 191.570 us; speedup vs baseline: 2.3468x; 2.3468x over previous
//
#include <hip/hip_runtime.h>
#include <hip/hip_fp16.h>
#include <cstdint>
#include <cstring>

typedef unsigned int uint;

#define BSHIFT 8          // 256 nodes per bucket
#define NBUCK 512         // max buckets (N up to 131072)
#define TILE 4096         // scatter tile
#define FUSE_T 1024       // fused sort+gat block size
#define LS_T 512          // fused linear+scatter block size
#define SORT_CAP 5120     // per-bucket capacity (mean ~4092, +16 sigma)

__device__ __forceinline__ float leaky02(float x) { return x > 0.f ? x : 0.2f * x; }
__device__ __forceinline__ float bflo(uint u) { return __uint_as_float(u << 16); }
__device__ __forceinline__ float bfhi(uint u) { return __uint_as_float(u & 0xffff0000u); }

__device__ __forceinline__ uint pack_bf16x2(float a, float b) {
    uint ua = __float_as_uint(a), ub = __float_as_uint(b);
    ua += 0x7fffu + ((ua >> 16) & 1u);
    ub += 0x7fffu + ((ub >> 16) & 1u);
    return (ua >> 16) | (ub & 0xffff0000u);
}

__device__ __forceinline__ uint packh2(float a, float b) {
    __half ha = __float2half_rn(a), hb = __float2half_rn(b);
    unsigned short ua, ub;
    memcpy(&ua, &ha, 2);
    memcpy(&ub, &hb, 2);
    return (uint)ua | ((uint)ub << 16);
}

// select half #head (0..3) from a uint2 of 4 packed halves via bit ops
__device__ __forceinline__ float h2f_sel(uint2 xw, int head) {
    uint wrd = (head & 2) ? xw.y : xw.x;
    unsigned short us = (unsigned short)((head & 1) ? (wrd >> 16) : (wrd & 0xffffu));
    __half hh; memcpy(&hh, &us, 2);
    return __half2float(hh);
}

// ---------------------------------------------------------------------------
// FUSED k_linear + kb_scatter (independent work, block-range split).
// Blocks [0, Lb): linear — 64 nodes/block. Blocks [Lb, Lb+Sb): scatter —
// one 4096-edge tile/block, direct-write placement (R13-measured neutral,
// simpler). cursor/sums/sumsq/flags zeroed by hipMemsetAsync before launch.
// ---------------------------------------------------------------------------
__global__ void k_linscat(const float* __restrict__ x, const float* __restrict__ W,
                          const float* __restrict__ att_s, const float* __restrict__ att_d,
                          uint* __restrict__ h, float* __restrict__ a_src,
                          float* __restrict__ a_dst,
                          const int* __restrict__ src, const int* __restrict__ dst, int E,
                          int* __restrict__ cursor, uint* __restrict__ pairs,
                          const int* __restrict__ lut, int nlut,
                          unsigned char* __restrict__ flags, int N, int Lb) {
    int tid = threadIdx.x;  // 512
    if (blockIdx.x < Lb) {
        // ---------------- linear part: 64 nodes ----------------
        __shared__ float sx[64][16];
        __shared__ float sWs[64], sWd[64];
        int j = tid & 63;       // channel pair
        int sub = tid >> 6;     // wave id 0..7 -> node subgroup
        int n0 = blockIdx.x * 64;

        float2 wreg[16];
#pragma unroll
        for (int k = 0; k < 16; k++) wreg[k] = ((const float2*)(W + k * 128))[j];

        if (tid < 256) {
            int row = tid >> 2;
            if (n0 + row < N)
                ((float4*)sx)[tid] = ((const float4*)(x + (size_t)n0 * 16))[tid];
        } else if (tid < 320) {
            int t = tid - 256;              // t = k*4 + hh
            int k = t >> 2, hh = t & 3;
            float s1 = 0.f, s2 = 0.f;
            for (int c = 0; c < 32; c++) {
                float wv = W[k * 128 + hh * 32 + c];
                s1 += wv * att_s[hh * 32 + c];
                s2 += wv * att_d[hh * 32 + c];
            }
            sWs[t] = s1;
            sWd[t] = s2;
        }
        __syncthreads();

#pragma unroll
        for (int i = 0; i < 8; i++) {
            int loc = sub + i * 8;
            int n = n0 + loc;
            if (n >= N) break;
            float acc0 = 0.f, acc1 = 0.f;
#pragma unroll
            for (int k = 0; k < 16; k++) {
                float xk = sx[loc][k];
                acc0 += xk * wreg[k].x;
                acc1 += xk * wreg[k].y;
            }
            h[(size_t)n * 64 + j] = pack_bf16x2(acc0, acc1);
        }

        // a_src / a_dst: thread t -> (node tid>>3, head (tid>>1)&3, sd tid&1)
        int loc2 = tid >> 3, hh = (tid >> 1) & 3, sd = tid & 1;
        int n2 = n0 + loc2;
        if (n2 < N) {
            const float* Wm = sd ? sWd : sWs;
            float acc = 0.f;
#pragma unroll
            for (int k = 0; k < 16; k++) acc += sx[loc2][k] * Wm[k * 4 + hh];
            if (sd) a_dst[n2 * 4 + hh] = acc;
            else    a_src[n2 * 4 + hh] = acc;
        }
    } else {
        // ---------------- scatter part: one 4096-edge tile, direct write ---
        __shared__ int tileCnt[NBUCK], tileCnt2[NBUCK], gbase[NBUCK];
        int bid = blockIdx.x - Lb;
        int t0 = bid * TILE;
        if (bid == 0) {
            for (int k = tid; k < nlut; k += LS_T) flags[lut[k]] = 1;
        }
        tileCnt[tid] = 0;
        tileCnt2[tid] = 0;
        __syncthreads();
        int dreg[8], sreg[8];
#pragma unroll
        for (int jj = 0; jj < 8; jj++) {
            int idx = t0 + jj * LS_T + tid;
            if (idx < E) {
                dreg[jj] = dst[idx];
                sreg[jj] = src[idx];
                atomicAdd(&tileCnt[dreg[jj] >> BSHIFT], 1);
            } else dreg[jj] = -1;
        }
        __syncthreads();
        int v = tileCnt[tid];
        if (v > 0) gbase[tid] = atomicAdd(&cursor[tid], v);
        __syncthreads();
#pragma unroll
        for (int jj = 0; jj < 8; jj++) {
            if (dreg[jj] >= 0) {
                int bk = dreg[jj] >> BSHIFT;
                int r = atomicAdd(&tileCnt2[bk], 1);
                int pos = gbase[bk] + r;
                if (pos < SORT_CAP)
                    pairs[(size_t)bk * SORT_CAP + pos] =
                        ((uint)sreg[jj] << BSHIFT) | (uint)(dreg[jj] & 255);
            }
        }
    }
}

// ---------------------------------------------------------------------------
// FUSED per-bucket sort + GAT aggregation + BN stats.
// launch_bounds(1024, 8): VGPR cap 64 -> 2 blocks/CU, 391 blocks in one round.
// BN via register sv/sq + ONE post-loop reduction (R11/R13-measured, 73.4 us).
// Mild spill (~10 MB writes) is overlappable and measured-free.
// MEASURED-DEAD alternatives (do not retry): in-loop BN combine (R12 +22us),
// launch_bounds(1024,4) (R10: 1 blk/CU, +8us), fp8 h (R5: absmax fail),
// last-block fence fusion (R14: __threadfence L2-invalidation, +256us).
// ---------------------------------------------------------------------------
__global__ void __launch_bounds__(1024, 8) kb_sortgat(
                           const uint* __restrict__ pairs, const int* __restrict__ cursor,
                           const float* __restrict__ a_src, const float* __restrict__ a_dst,
                           const uint* __restrict__ h, const float* __restrict__ bias,
                           const unsigned char* __restrict__ flags,
                           uint* __restrict__ hagg,
                           float* __restrict__ sums, float* __restrict__ sumsq, int N) {
    __shared__ int cnt[256], off0[256], degl[256];
    __shared__ int wsum[4], wbase[4];
    __shared__ uint lcode[SORT_CAP];      // src per edge; reused as BN-reduce buf
    __shared__ uint2 wlds[SORT_CAP];      // fp16x4 weights per edge
    __shared__ float4 sad[256];
    __shared__ float4 sbias[32];
    int tid = threadIdx.x;  // 1024
    int l = tid & 63, w = tid >> 6;
    int b = blockIdx.x;
    int n0 = b << BSHIFT;
    int nn = min(256, N - n0);
    int ebase = b * SORT_CAP;
    int ecnt = cursor[b];
    if (ecnt > SORT_CAP) ecnt = SORT_CAP;
    if (tid < 256) cnt[tid] = 0;
    if (tid < nn) sad[tid] = ((const float4*)a_dst)[n0 + tid];
    if (tid >= 992) sbias[tid - 992] = ((const float4*)bias)[tid - 992];
    __syncthreads();
    for (int k = tid; k < ecnt; k += FUSE_T)
        atomicAdd(&cnt[pairs[ebase + k] & 255], 1);
    __syncthreads();
    // wave-shfl exclusive scan over 256 entries (waves 0..3)
    int v = (tid < 256) ? cnt[tid] : 0;
    int s = v;
#pragma unroll
    for (int off = 1; off < 64; off <<= 1) {
        int t = __shfl_up(s, off);
        if (l >= off) s += t;
    }
    if (tid < 256 && l == 63) wsum[w] = s;
    __syncthreads();
    if (tid < 4) {
        int base = 0;
        for (int i = 0; i < tid; i++) base += wsum[i];
        wbase[tid] = base;
    }
    __syncthreads();
    if (tid < 256) {
        off0[tid] = s - v + wbase[w];
        degl[tid] = v;
    }
    __syncthreads();
    if (tid < 256) cnt[tid] = 0;
    __syncthreads();
    // single pass: scatter src + compute weights (a_src is L2-resident)
    for (int k = tid; k < ecnt; k += FUSE_T) {
        uint p = pairs[ebase + k];
        int ln = p & 255;
        int src = (int)(p >> BSHIFT);
        int r = atomicAdd(&cnt[ln], 1);
        int pos = off0[ln] + r;
        lcode[pos] = (uint)src;
        float4 as = ((const float4*)a_src)[src];
        float4 ad = sad[ln];
        wlds[pos] = make_uint2(
            packh2(__expf(leaky02(as.x + ad.x)), __expf(leaky02(as.y + ad.y))),
            packh2(__expf(leaky02(as.z + ad.z)), __expf(leaky02(as.w + ad.w))));
    }
    __syncthreads();
    // aggregation: 16 waves x 4 nodes/wave = 64 nodes per pass, 4 passes
    int q = l >> 4;
    int l16 = l & 15;
    int head = l16 >> 2;
    float sv[8], sq[8];
#pragma unroll
    for (int j = 0; j < 8; j++) { sv[j] = 0.f; sq[j] = 0.f; }
    for (int pass = 0; pass < 4; pass++) {
        int ln = pass * 64 + w * 4 + q;
        if (ln >= nn) continue;   // no barriers below in this loop: safe
        int d = n0 + ln;
        int ebs = off0[ln];
        int deg = degl[ln];
        float asv = a_src[d * 4 + head];
        float adv = ((const float*)sad)[ln * 4 + head];
        float wslf = __expf(leaky02(asv + adv));
        uint4 u = ((const uint4*)(h + (size_t)d * 64))[l16];
        float sum = wslf;
        float2 a01 = make_float2(wslf * bflo(u.x), wslf * bfhi(u.x));
        float2 a23 = make_float2(wslf * bflo(u.y), wslf * bfhi(u.y));
        float2 a45 = make_float2(wslf * bflo(u.z), wslf * bfhi(u.z));
        float2 a67 = make_float2(wslf * bflo(u.w), wslf * bfhi(u.w));

        int i = 0;
        for (; i + 1 < deg; i += 2) {
            uint p0 = lcode[ebs + i];
            uint p1 = lcode[ebs + i + 1];
            float w0 = h2f_sel(wlds[ebs + i], head);
            float w1 = h2f_sel(wlds[ebs + i + 1], head);
            uint4 u0 = ((const uint4*)(h + (size_t)p0 * 64))[l16];
            uint4 u1 = ((const uint4*)(h + (size_t)p1 * 64))[l16];
            sum += w0 + w1;
            float2 w02 = {w0, w0}, w12 = {w1, w1};
            a01 += make_float2(bflo(u0.x), bfhi(u0.x)) * w02
                 + make_float2(bflo(u1.x), bfhi(u1.x)) * w12;
            a23 += make_float2(bflo(u0.y), bfhi(u0.y)) * w02
                 + make_float2(bflo(u1.y), bfhi(u1.y)) * w12;
            a45 += make_float2(bflo(u0.z), bfhi(u0.z)) * w02
                 + make_float2(bflo(u1.z), bfhi(u1.z)) * w12;
            a67 += make_float2(bflo(u0.w), bfhi(u0.w)) * w02
                 + make_float2(bflo(u1.w), bfhi(u1.w)) * w12;
        }
        if (i < deg) {
            uint p0 = lcode[ebs + i];
            float w0 = h2f_sel(wlds[ebs + i], head);
            uint4 u0 = ((const uint4*)(h + (size_t)p0 * 64))[l16];
            sum += w0;
            float2 w02 = {w0, w0};
            a01 += make_float2(bflo(u0.x), bfhi(u0.x)) * w02;
            a23 += make_float2(bflo(u0.y), bfhi(u0.y)) * w02;
            a45 += make_float2(bflo(u0.z), bfhi(u0.z)) * w02;
            a67 += make_float2(bflo(u0.w), bfhi(u0.w)) * w02;
        }
        float inv = 1.f / sum;
        float4 b0 = sbias[2 * l16];
        float4 b1 = sbias[2 * l16 + 1];
        float v0 = a01.x * inv + b0.x;
        float v1 = a01.y * inv + b0.y;
        float v2 = a23.x * inv + b0.z;
        float v3 = a23.y * inv + b0.w;
        float v4 = a45.x * inv + b1.x;
        float v5 = a45.y * inv + b1.y;
        float v6 = a67.x * inv + b1.z;
        float v7 = a67.y * inv + b1.w;
        sv[0] += v0; sq[0] += v0 * v0;
        sv[1] += v1; sq[1] += v1 * v1;
        sv[2] += v2; sq[2] += v2 * v2;
        sv[3] += v3; sq[3] += v3 * v3;
        sv[4] += v4; sq[4] += v4 * v4;
        sv[5] += v5; sq[5] += v5 * v5;
        sv[6] += v6; sq[6] += v6 * v6;
        sv[7] += v7; sq[7] += v7 * v7;
        if (flags[d]) {
            uint4 o;
            o.x = pack_bf16x2(v0, v1);
            o.y = pack_bf16x2(v2, v3);
            o.z = pack_bf16x2(v4, v5);
            o.w = pack_bf16x2(v6, v7);
            ((uint4*)(hagg + (size_t)d * 64))[l16] = o;
        }
    }
    // BN stats reduction: shfl over node-groups (lane bits 4,5), then LDS
    __syncthreads();               // all lcode/wlds reads done -> reuse lcode
#pragma unroll
    for (int j = 0; j < 8; j++) {
        sv[j] += __shfl_xor(sv[j], 16);
        sv[j] += __shfl_xor(sv[j], 32);
        sq[j] += __shfl_xor(sq[j], 16);
        sq[j] += __shfl_xor(sq[j], 32);
    }
    float* red = (float*)lcode;    // 256 rows x 16 floats = 16 KB <= 20 KB
    if (l < 16) {
#pragma unroll
        for (int j = 0; j < 8; j++) {
            red[(w * 16 + l) * 16 + j] = sv[j];
            red[(w * 16 + l) * 16 + 8 + j] = sq[j];
        }
    }
    __syncthreads();
    if (tid < 256) {
        int lg = tid >> 4, j = tid & 15;
        float tot = 0.f;
#pragma unroll
        for (int ww = 0; ww < 16; ww++) tot += red[(ww * 16 + lg) * 16 + j];
        if (j < 8) atomicAdd(&sums[lg * 8 + j], tot);
        else       atomicAdd(&sumsq[lg * 8 + j - 8], tot);
    }
}

// ---------------------------------------------------------------------------
// Per LUT node: BN + ReLU + MLP 128->32 (leaky 0.01) -> 1
// ---------------------------------------------------------------------------
__global__ void k_mlp(const uint* __restrict__ hagg, const int* __restrict__ lut,
                      const float* __restrict__ sums, const float* __restrict__ sumsq,
                      const float* __restrict__ gamma, const float* __restrict__ beta,
                      const float* __restrict__ W1, const float* __restrict__ b1,
                      const float* __restrict__ W2, const float* __restrict__ b2,
                      float* __restrict__ out, int N, int nlut) {
    int blk = blockIdx.x;
    if (blk >= nlut) return;
    int node = lut[blk];
    int lane = threadIdx.x;  // 64
    __shared__ float v[128];
    float invN = 1.f / (float)N;
    uint u = hagg[(size_t)node * 64 + lane];
    int c0 = 2 * lane, c1 = 2 * lane + 1;
    {
        float mean = sums[c0] * invN;
        float var = sumsq[c0] * invN - mean * mean;
        float val = (bflo(u) - mean) / sqrtf(var + 1e-5f) * gamma[c0] + beta[c0];
        v[c0] = fmaxf(val, 0.f);
        mean = sums[c1] * invN;
        var = sumsq[c1] * invN - mean * mean;
        val = (bfhi(u) - mean) / sqrtf(var + 1e-5f) * gamma[c1] + beta[c1];
        v[c1] = fmaxf(val, 0.f);
    }
    __syncthreads();
    float r = 0.f;
    if (lane < 32) {
        float z = b1[lane];
        for (int c = 0; c < 128; c++) z += v[c] * W1[c * 32 + lane];
        z = z > 0.f ? z : 0.01f * z;
        r = z * W2[lane];
    }
#pragma unroll
    for (int off = 16; off >= 1; off >>= 1) r += __shfl_xor(r, off);
    if (lane == 0) out[blk] = r + b2[0];
}

// ---------------------------------------------------------------------------
extern "C" void kernel_launch(void* const* d_in, const int* in_sizes, int n_in,
                              void* d_out, int out_size, void* d_ws, size_t ws_size,
                              hipStream_t stream) {
    const float* x     = (const float*)d_in[0];
    const int*   edges = (const int*)d_in[1];
    const int*   lut   = (const int*)d_in[2];
    const float* W_lin = (const float*)d_in[3];
    const float* att_s = (const float*)d_in[4];
    const float* att_d = (const float*)d_in[5];
    const float* bias  = (const float*)d_in[6];
    const float* gamma = (const float*)d_in[7];
    const float* beta  = (const float*)d_in[8];
    const float* W1    = (const float*)d_in[9];
    const float* b1    = (const float*)d_in[10];
    const float* W2    = (const float*)d_in[11];
    const float* b2    = (const float*)d_in[12];

    int N = in_sizes[0] / 16;
    int E = in_sizes[1] / 2;
    int nlut = in_sizes[2];
    int B = (N + 255) >> BSHIFT;   // 391 for N=100000
    int Lb = (N + 63) / 64;        // linear blocks (64 nodes each)
    int Sb = (E + TILE - 1) / TILE;

    const int* esrc = edges;
    const int* edst = edges + E;

    char* ws = (char*)d_ws;
    size_t off = 0;
    auto alloc = [&](size_t bytes) -> void* {
        void* p = ws + off;
        off += (bytes + 255) & ~(size_t)255;
        return p;
    };
    uint*  h       = (uint*)alloc((size_t)N * 64 * 4);          // bf16x2 [N,128]
    uint*  hagg    = (uint*)alloc((size_t)N * 64 * 4);          // bf16x2 [N,128]
    float* a_src   = (float*)alloc((size_t)N * 4 * 4);
    float* a_dst   = (float*)alloc((size_t)N * 4 * 4);
    uint*  pairs   = (uint*)alloc((size_t)B * SORT_CAP * 4);
    // contiguous zero-region: cursor | sums | sumsq | flags
    char*  zbase   = ws + off;
    int*   cursor  = (int*)alloc((size_t)NBUCK * 4);
    float* sums    = (float*)alloc(128 * 4);
    float* sumsq   = (float*)alloc(128 * 4);
    unsigned char* flags = (unsigned char*)alloc((size_t)N);
    size_t zspan = (size_t)((ws + off) - zbase);

    hipMemsetAsync(zbase, 0, zspan, stream);
    k_linscat<<<Lb + Sb, LS_T, 0, stream>>>(x, W_lin, att_s, att_d, h, a_src, a_dst,
                                            esrc, edst, E, cursor, pairs,
                                            lut, nlut, flags, N, Lb);
    kb_sortgat<<<B, FUSE_T, 0, stream>>>(pairs, cursor, a_src, a_dst, h, bias,
                                         flags, hagg, sums, sumsq, N);
    k_mlp<<<nlut, 64, 0, stream>>>(hagg, lut, sums, sumsq, gamma, beta, W1, b1, W2, b2,
                                   (float*)d_out, N, nlut);
}